// Round 3
// baseline (357.127 us; speedup 1.0000x reference)
//
#include <hip/hip_runtime.h>
#include <math.h>

#define HH 224
#define WW 224
#define TH 32
#define TW 32
#define TILES_X 7
#define TILES_PER_IMG 49
#define HALO 36

// ---------------- mask: which channels are augmented ----------------
__global__ void mask_kernel(const int* __restrict__ channel_idx, int n_aug, int c,
                            int* __restrict__ mask) {
    int t = threadIdx.x;
    for (int i = t; i < c; i += blockDim.x) mask[i] = 0;
    __syncthreads();
    for (int i = t; i < n_aug; i += blockDim.x) mask[channel_idx[i]] = 1;
}

// ---------------- copy non-augmented channels, float4 ----------------
__global__ __launch_bounds__(256) void copy_kernel(const float4* __restrict__ M4,
                                                   const int* __restrict__ mask,
                                                   float4* __restrict__ out4,
                                                   int c, int bpc) {
    int chan = blockIdx.x / bpc;        // 0 .. b*c-1
    int blk  = blockIdx.x % bpc;
    int ch   = chan % c;
    if (mask[ch]) return;               // augmented channel: skip (overwritten later)
    int off = blk * 256 + threadIdx.x;  // 0 .. 12543
    size_t idx = (size_t)chan * (HH * WW / 4) + off;
    out4[idx] = M4[idx];
}

__device__ __forceinline__ int reflect_idx(int v, int n) {
    if (v < 0) v = -v;
    if (v > n - 1) v = 2 * (n - 1) - v;
    return v;
}

// ---------------- fused warp + blur + noise per 32x32 tile ----------------
__global__ __launch_bounds__(256) void augment_kernel(
        const float* __restrict__ M, const int* __restrict__ channel_idx,
        const float* __restrict__ aug_u, const float* __restrict__ noise,
        float* __restrict__ out, int c, int n_aug) {
    const int tile = blockIdx.x;            // 0..48
    const int n    = blockIdx.y;            // 0..N-1
    const int a    = n % n_aug;
    const int bi   = n / n_aug;
    const int ch   = channel_idx[a];
    const int y0   = (tile / TILES_X) * TH;
    const int x0   = (tile % TILES_X) * TW;
    const int tid  = threadIdx.x;

    const float* __restrict__ img = M + ((size_t)bi * c + ch) * (HH * WW);
    const float* __restrict__ u   = aug_u + (size_t)n * 7;

    // ---- per-image params (all threads compute identically; cheap) ----
    const float u0 = u[0], u1 = u[1], u2 = u[2], u3 = u[3], u4 = u[4], u5 = u[5], u6 = u[6];
    const float area  = (float)(HH * WW) * (0.8f + 0.2f * u0);
    const float lo    = logf(0.75f);
    const float hi    = logf(4.0f / 3.0f);
    const float ratio = expf(lo + (hi - lo) * u1);
    float wc = sqrtf(area * ratio);
    float hc = sqrtf(area / ratio);
    wc = fminf(fmaxf(wc, 1.0f), (float)WW);
    hc = fminf(fmaxf(hc, 1.0f), (float)HH);
    const float fi    = u2 * ((float)HH - hc);
    const float fj    = u3 * ((float)WW - wc);
    const bool  flip  = u4 < 0.5f;
    const float angle = u5 * 3.14159274101257324f;
    const float sigma = 0.1f + 1.9f * u6;
    const float ca = cosf(angle), sa = sinf(angle);
    const float syk = hc / (float)HH;
    const float sxk = wc / (float)WW;

    // gaussian weights
    float wk[5];
    float wsum = 0.f;
    #pragma unroll
    for (int k = 0; k < 5; ++k) {
        float d = (float)k - 2.0f;
        wk[k] = expf(-(d * d) / (2.0f * sigma * sigma));
        wsum += wk[k];
    }
    #pragma unroll
    for (int k = 0; k < 5; ++k) wk[k] /= wsum;

    __shared__ float Wt[HALO][HALO + 1];
    __shared__ float Tmp[TH][HALO + 1];

    const float cc = ((float)HH - 1.0f) * 0.5f;  // 111.5

    // ---- warp into halo tile (values stored at reflect-mapped coords) ----
    for (int idx = tid; idx < HALO * HALO; idx += 256) {
        int hy = idx / HALO, hx = idx % HALO;
        int ry = reflect_idx(y0 + hy - 2, HH);
        int rx = reflect_idx(x0 + hx - 2, WW);
        float dy = (float)ry - cc, dx = (float)rx - cc;
        float yr = ca * dy + sa * dx + cc;
        float xr = -sa * dy + ca * dx + cc;
        float val = 0.f;
        if (yr >= -0.5f && yr <= (float)HH - 0.5f && xr >= -0.5f && xr <= (float)WW - 0.5f) {
            float xf = flip ? ((float)WW - 1.0f) - xr : xr;
            float sy = (yr + 0.5f) * syk - 0.5f + fi;
            float sx = (xf + 0.5f) * sxk - 0.5f + fj;
            float fy = floorf(sy), fx = floorf(sx);
            float wy = sy - fy, wx = sx - fx;
            int y0i = min(max((int)fy, 0), HH - 1);
            int x0i = min(max((int)fx, 0), WW - 1);
            int y1i = min(y0i + 1, HH - 1);
            int x1i = min(x0i + 1, WW - 1);
            const float* r0 = img + (size_t)y0i * WW;
            const float* r1 = img + (size_t)y1i * WW;
            float v00 = r0[x0i], v01 = r0[x1i];
            float v10 = r1[x0i], v11 = r1[x1i];
            float top = v00 * (1.f - wx) + v01 * wx;
            float bot = v10 * (1.f - wx) + v11 * wx;
            val = top * (1.f - wy) + bot * wy;
        }
        Wt[hy][hx] = val;
    }
    __syncthreads();

    // ---- vertical blur: 32 rows x 36 cols ----
    for (int idx = tid; idx < TH * HALO; idx += 256) {
        int y = idx / HALO, cx = idx % HALO;
        float s = wk[0] * Wt[y][cx] + wk[1] * Wt[y + 1][cx] + wk[2] * Wt[y + 2][cx]
                + wk[3] * Wt[y + 3][cx] + wk[4] * Wt[y + 4][cx];
        Tmp[y][cx] = s;
    }
    __syncthreads();

    // ---- horizontal blur + noise + write ----
    const float* __restrict__ npz = noise + (size_t)n * (HH * WW);
    float* __restrict__ op = out + ((size_t)bi * c + ch) * (HH * WW);
    for (int idx = tid; idx < TH * TW; idx += 256) {
        int y = idx / TW, x = idx % TW;
        float s = wk[0] * Tmp[y][x] + wk[1] * Tmp[y][x + 1] + wk[2] * Tmp[y][x + 2]
                + wk[3] * Tmp[y][x + 3] + wk[4] * Tmp[y][x + 4];
        int gy = y0 + y, gx = x0 + x;
        op[(size_t)gy * WW + gx] = s + 0.05f * npz[(size_t)gy * WW + gx];
    }
}

extern "C" void kernel_launch(void* const* d_in, const int* in_sizes, int n_in,
                              void* d_out, int out_size, void* d_ws, size_t ws_size,
                              hipStream_t stream) {
    const float* M           = (const float*)d_in[0];
    const int*   channel_idx = (const int*)d_in[1];
    const float* aug_u       = (const float*)d_in[2];
    const float* noise       = (const float*)d_in[3];
    float* out = (float*)d_out;

    const int n_aug = in_sizes[1];
    const int b     = in_sizes[2] / (n_aug * 7);
    const int c     = in_sizes[0] / (b * HH * WW);
    const int N     = b * n_aug;

    int* mask = (int*)d_ws;

    mask_kernel<<<1, 256, 0, stream>>>(channel_idx, n_aug, c, mask);

    const int nchan = b * c;
    const int bpc   = (HH * WW / 4 + 255) / 256;  // 49 blocks per channel
    copy_kernel<<<nchan * bpc, 256, 0, stream>>>((const float4*)M, mask, (float4*)out, c, bpc);

    dim3 grid(TILES_PER_IMG, N);
    augment_kernel<<<grid, 256, 0, stream>>>(M, channel_idx, aug_u, noise, out, c, n_aug);
}

// Round 4
// 330.520 us; speedup vs baseline: 1.0805x; 1.0805x over previous
//
#include <hip/hip_runtime.h>
#include <math.h>

#define HH 224
#define WW 224
#define TH 32
#define TW 32
#define TILES_X 7
#define TILES_PER_IMG 49
#define HALO 36

struct __align__(16) ImgParams {
    float ca, sa, ay, by;   // rotation + y-affine (sy = ay*yr + by)
    float ax, bx, w0, w1;   // x-affine (flip folded in) + blur taps
    float w2, w3, w4, pad;
};

// ---------------- mask: which channels are augmented ----------------
__global__ void mask_kernel(const int* __restrict__ channel_idx, int n_aug, int c,
                            int* __restrict__ mask) {
    int t = threadIdx.x;
    for (int i = t; i < c; i += blockDim.x) mask[i] = 0;
    __syncthreads();
    for (int i = t; i < n_aug; i += blockDim.x) mask[channel_idx[i]] = 1;
}

// ---------------- per-image params: all transcendentals, once per image ----------------
__global__ void params_kernel(const float* __restrict__ aug_u,
                              ImgParams* __restrict__ params, int N) {
    int n = blockIdx.x * blockDim.x + threadIdx.x;
    if (n >= N) return;
    const float* u = aug_u + (size_t)n * 7;
    const float u0 = u[0], u1 = u[1], u2 = u[2], u3 = u[3], u4 = u[4], u5 = u[5], u6 = u[6];

    const float area  = (float)(HH * WW) * (0.8f + 0.2f * u0);
    const float lo    = logf(0.75f);
    const float hi    = logf(4.0f / 3.0f);
    const float ratio = expf(lo + (hi - lo) * u1);
    float wc = sqrtf(area * ratio);
    float hc = sqrtf(area / ratio);
    wc = fminf(fmaxf(wc, 1.0f), (float)WW);
    hc = fminf(fmaxf(hc, 1.0f), (float)HH);
    const float fi    = u2 * ((float)HH - hc);
    const float fj    = u3 * ((float)WW - wc);
    const bool  flip  = u4 < 0.5f;
    const float angle = u5 * 3.14159274101257324f;
    const float sigma = 0.1f + 1.9f * u6;

    ImgParams p;
    p.ca = cosf(angle);
    p.sa = sinf(angle);
    const float syk = hc / (float)HH;
    const float sxk = wc / (float)WW;
    p.ay = syk;
    p.by = 0.5f * syk - 0.5f + fi;
    if (flip) {
        p.ax = -sxk;
        p.bx = ((float)WW - 0.5f) * sxk - 0.5f + fj;
    } else {
        p.ax = sxk;
        p.bx = 0.5f * sxk - 0.5f + fj;
    }
    float wk[5], wsum = 0.f;
    const float inv2s2 = 1.0f / (2.0f * sigma * sigma);
    #pragma unroll
    for (int k = 0; k < 5; ++k) {
        float d = (float)k - 2.0f;
        wk[k] = expf(-(d * d) * inv2s2);
        wsum += wk[k];
    }
    float inv = 1.0f / wsum;
    p.w0 = wk[0] * inv; p.w1 = wk[1] * inv; p.w2 = wk[2] * inv;
    p.w3 = wk[3] * inv; p.w4 = wk[4] * inv;
    p.pad = 0.f;
    params[n] = p;
}

// ---------------- copy non-augmented channels, float4 ----------------
__global__ __launch_bounds__(256) void copy_kernel(const float4* __restrict__ M4,
                                                   const int* __restrict__ mask,
                                                   float4* __restrict__ out4,
                                                   int c, int bpc) {
    int chan = blockIdx.x / bpc;
    int blk  = blockIdx.x % bpc;
    int ch   = chan % c;
    if (mask[ch]) return;
    int off = blk * 256 + threadIdx.x;
    size_t idx = (size_t)chan * (HH * WW / 4) + off;
    out4[idx] = M4[idx];
}

// ---------------- fused warp + blur + noise per 32x32 tile ----------------
__global__ __launch_bounds__(256) void augment_kernel(
        const float* __restrict__ M, const int* __restrict__ channel_idx,
        const ImgParams* __restrict__ params, const float* __restrict__ noise,
        float* __restrict__ out, int c, int n_aug) {
    const int tile = blockIdx.x;            // 0..48
    const int a    = blockIdx.y;            // 0..n_aug-1
    const int bi   = blockIdx.z;            // 0..b-1
    const int n    = bi * n_aug + a;
    const int ch   = channel_idx[a];
    const int y0   = (tile / TILES_X) * TH;
    const int x0   = (tile % TILES_X) * TW;
    const int tid  = threadIdx.x;

    const ImgParams P = params[n];          // uniform -> scalar loads

    const float* __restrict__ img = M + ((size_t)bi * c + ch) * (HH * WW);

    __shared__ float Wt[HALO][HALO + 1];
    __shared__ float Tmp[TH][HALO + 1];

    const float cc = 111.5f;

    // ---- warp into halo tile (values stored at reflect-mapped coords) ----
    {
        int hy = tid / HALO, hx = tid - hy * HALO;   // one div total
        #pragma unroll
        for (int it = 0; it < 6; ++it) {
            int idx = it * 256 + tid;
            if (idx < HALO * HALO) {
                int vy = y0 + hy - 2;
                int vx = x0 + hx - 2;
                int ay_ = abs(vy);  int ry = min(ay_, 2 * (HH - 1) - ay_);  // reflect
                int ax_ = abs(vx);  int rx = min(ax_, 2 * (WW - 1) - ax_);
                float dy = (float)ry - cc, dx = (float)rx - cc;
                float yr = P.ca * dy + P.sa * dx + cc;
                float xr = P.ca * dx - P.sa * dy + cc;
                float val = 0.f;
                if (yr >= -0.5f && yr <= (float)HH - 0.5f &&
                    xr >= -0.5f && xr <= (float)WW - 0.5f) {
                    float sy = P.ay * yr + P.by;
                    float sx = P.ax * xr + P.bx;
                    float fy = floorf(sy), fx = floorf(sx);
                    float wy = sy - fy, wx = sx - fx;
                    int y0i = min(max((int)fy, 0), HH - 1);
                    int x0i = min(max((int)fx, 0), WW - 1);
                    int y1i = min(y0i + 1, HH - 1);
                    int x1i = min(x0i + 1, WW - 1);
                    const float* r0 = img + y0i * WW;
                    const float* r1 = img + y1i * WW;
                    float v00 = r0[x0i], v01 = r0[x1i];
                    float v10 = r1[x0i], v11 = r1[x1i];
                    float top = v00 + (v01 - v00) * wx;
                    float bot = v10 + (v11 - v10) * wx;
                    val = top + (bot - top) * wy;
                }
                Wt[hy][hx] = val;
            }
            hy += 7; hx += 4; if (hx >= HALO) { hx -= HALO; hy += 1; }
        }
    }
    __syncthreads();

    // ---- vertical blur: 32 rows x 36 cols ----
    {
        int vy = tid / HALO, vx = tid - vy * HALO;
        #pragma unroll
        for (int it = 0; it < 5; ++it) {
            int idx = it * 256 + tid;
            if (idx < TH * HALO) {
                float s = P.w0 * Wt[vy][vx]     + P.w1 * Wt[vy + 1][vx]
                        + P.w2 * Wt[vy + 2][vx] + P.w3 * Wt[vy + 3][vx]
                        + P.w4 * Wt[vy + 4][vx];
                Tmp[vy][vx] = s;
            }
            vy += 7; vx += 4; if (vx >= HALO) { vx -= HALO; vy += 1; }
        }
    }
    __syncthreads();

    // ---- horizontal blur + noise + write ----
    const float* __restrict__ npz = noise + (size_t)n * (HH * WW);
    float* __restrict__ op = out + ((size_t)bi * c + ch) * (HH * WW);
    #pragma unroll
    for (int it = 0; it < 4; ++it) {
        int idx = it * 256 + tid;
        int y = idx >> 5, x = idx & 31;
        float s = P.w0 * Tmp[y][x]     + P.w1 * Tmp[y][x + 1] + P.w2 * Tmp[y][x + 2]
                + P.w3 * Tmp[y][x + 3] + P.w4 * Tmp[y][x + 4];
        int gy = y0 + y, gx = x0 + x;
        size_t o = (size_t)gy * WW + gx;
        op[o] = s + 0.05f * npz[o];
    }
}

extern "C" void kernel_launch(void* const* d_in, const int* in_sizes, int n_in,
                              void* d_out, int out_size, void* d_ws, size_t ws_size,
                              hipStream_t stream) {
    const float* M           = (const float*)d_in[0];
    const int*   channel_idx = (const int*)d_in[1];
    const float* aug_u       = (const float*)d_in[2];
    const float* noise       = (const float*)d_in[3];
    float* out = (float*)d_out;

    const int n_aug = in_sizes[1];
    const int b     = in_sizes[2] / (n_aug * 7);
    const int c     = in_sizes[0] / (b * HH * WW);
    const int N     = b * n_aug;

    int* mask = (int*)d_ws;
    ImgParams* params = (ImgParams*)((char*)d_ws + 4096);

    mask_kernel<<<1, 256, 0, stream>>>(channel_idx, n_aug, c, mask);
    params_kernel<<<(N + 255) / 256, 256, 0, stream>>>(aug_u, params, N);

    const int nchan = b * c;
    const int bpc   = (HH * WW / 4 + 255) / 256;  // 49 blocks per channel
    copy_kernel<<<nchan * bpc, 256, 0, stream>>>((const float4*)M, mask, (float4*)out, c, bpc);

    dim3 grid(TILES_PER_IMG, n_aug, b);
    augment_kernel<<<grid, 256, 0, stream>>>(M, channel_idx, params, noise, out, c, n_aug);
}